// Round 1
// baseline (533.916 us; speedup 1.0000x reference)
//
#include <hip/hip_runtime.h>
#include <hip/hip_bf16.h>

#define CC 128
#define BB 4
#define NN 4096

typedef __bf16 bf16x8 __attribute__((ext_vector_type(8)));
typedef float f32x4 __attribute__((ext_vector_type(4)));
typedef unsigned short ushortx8 __attribute__((ext_vector_type(8)));

__device__ __forceinline__ float bf2f(unsigned short u) {
    unsigned int i = ((unsigned int)u) << 16;
    return __builtin_bit_cast(float, i);
}
__device__ __forceinline__ unsigned short f2bf(float f) {
    unsigned int i = __builtin_bit_cast(unsigned int, f);
    i = i + 0x7fffu + ((i >> 16) & 1u);   // RNE; inputs finite
    return (unsigned short)(i >> 16);
}

// ---------------- Kernel 1: QKV projections ----------------
// Q[b][n][c] = theta, K[b][n][c] = phi  (row-major over c, MFMA-frag friendly)
// V[b][c][n] = g                        (d-major == V^T, PV-B-frag friendly)
__global__ __launch_bounds__(256) void proj_qkv(
    const float* __restrict__ x,
    const float* __restrict__ w_t, const float* __restrict__ b_t,
    const float* __restrict__ w_p, const float* __restrict__ b_p,
    const float* __restrict__ w_g, const float* __restrict__ b_g,
    unsigned short* __restrict__ Q,
    unsigned short* __restrict__ K,
    unsigned short* __restrict__ V)
{
    const int bid = blockIdx.x;
    const int b   = bid >> 6;
    const int n0  = (bid & 63) << 6;
    const int p   = threadIdx.x & 63;
    const int cg  = threadIdx.x >> 6;   // 0..3: c-quarter
    const int n   = n0 + p;

    // x[:, n] into registers (loads coalesced across lanes: consecutive n)
    float xr[CC];
    const float* xb = x + (size_t)b * CC * NN + n;
#pragma unroll
    for (int k = 0; k < CC; ++k) xr[k] = xb[(size_t)k * NN];

    const int c0 = cg * 32;
    for (int ci = 0; ci < 32; ++ci) {
        const int c = c0 + ci;
        const float* wt = w_t + c * CC;   // uniform across wave -> s_loads
        const float* wp = w_p + c * CC;
        const float* wg = w_g + c * CC;
        float at = b_t[c], ap = b_p[c], ag = b_g[c];
#pragma unroll
        for (int k = 0; k < CC; ++k) {
            const float xv = xr[k];
            at = fmaf(wt[k], xv, at);
            ap = fmaf(wp[k], xv, ap);
            ag = fmaf(wg[k], xv, ag);
        }
        Q[((size_t)b * NN + n) * CC + c] = f2bf(at);
        K[((size_t)b * NN + n) * CC + c] = f2bf(ap);
        V[((size_t)b * CC + c) * NN + n] = f2bf(ag);
    }
}

// ---------------- Kernel 2: flash attention ----------------
// 4 waves/block; wave owns 16 q-rows; KV tile = 64 keys; D = 128; no softmax scale.
__global__ __launch_bounds__(256) void flash_attn(
    const unsigned short* __restrict__ Q,   // [B][N][C]
    const unsigned short* __restrict__ K,   // [B][N][C]
    const unsigned short* __restrict__ V,   // [B][C][N]  (= V^T)
    unsigned short* __restrict__ O)         // [B][N][C]
{
    // K rows 256B, V^T rows 128B: both XOR-swizzled (G4) to kill the
    // 16-lane same-bank-column conflict on ds_read_b128.
    __shared__ alignas(16) unsigned short Ks[64 * 128];
    __shared__ alignas(16) unsigned short Vs[128 * 64];
    __shared__ alignas(16) unsigned short Ps[4][16][72];  // pad 64->72 (2-way, free)

    const int tid = threadIdx.x;
    const int bid = blockIdx.x;
    const int b    = bid >> 6;
    const int n_q0 = (bid & 63) << 6;
    const int wid  = tid >> 6;
    const int l    = tid & 63;
    const int lr   = l & 15;   // row/col within 16
    const int lg   = l >> 4;   // k-group 0..3

    // Q fragments: A[row=lr][k = kk*32 + lg*8 + j]
    bf16x8 qf[4];
    {
        const unsigned short* qrow = Q + ((size_t)b * NN + (n_q0 + wid * 16 + lr)) * CC;
#pragma unroll
        for (int kk = 0; kk < 4; ++kk)
            qf[kk] = __builtin_bit_cast(bf16x8,
                *reinterpret_cast<const ushortx8*>(qrow + kk * 32 + lg * 8));
    }

    f32x4 Oa[8];
#pragma unroll
    for (int i = 0; i < 8; ++i) Oa[i] = (f32x4){0.f, 0.f, 0.f, 0.f};
    float m_run[4], l_run[4];
#pragma unroll
    for (int r = 0; r < 4; ++r) { m_run[r] = -3.0e38f; l_run[r] = 0.f; }

    for (int kt = 0; kt < NN / 64; ++kt) {
        const int m0 = kt * 64;
        __syncthreads();   // previous tile's LDS reads done
        // stage K tile (64x128) + V^T tile (128x64): 16KB each, 4x16B per thread
#pragma unroll
        for (int j = 0; j < 4; ++j) {
            const int i = tid + j * 256;   // 16B-chunk id, 0..1023
            {
                const int r = i >> 4;
                const int c = (i & 15) * 8;
                const ushortx8 u = *reinterpret_cast<const ushortx8*>(
                    K + ((size_t)b * NN + m0 + r) * CC + c);
                *reinterpret_cast<ushortx8*>(&Ks[r * 128 + (c ^ ((r & 7) << 3))]) = u;
            }
            {
                const int d = i >> 3;
                const int m = (i & 7) * 8;
                const ushortx8 u = *reinterpret_cast<const ushortx8*>(
                    V + ((size_t)b * CC + d) * NN + m0 + m);
                *reinterpret_cast<ushortx8*>(&Vs[d * 64 + (m ^ ((d & 7) << 3))]) = u;
            }
        }
        __syncthreads();

        // S = Q K^T : 16q x 64keys as 4 subtiles
        f32x4 acc[4];
#pragma unroll
        for (int ks = 0; ks < 4; ++ks) {
            acc[ks] = (f32x4){0.f, 0.f, 0.f, 0.f};
#pragma unroll
            for (int kk = 0; kk < 4; ++kk) {
                const int r = ks * 16 + lr;          // key row in tile
                const int c = kk * 32 + lg * 8;      // k offset
                bf16x8 kf = __builtin_bit_cast(bf16x8,
                    *reinterpret_cast<const ushortx8*>(&Ks[r * 128 + (c ^ ((r & 7) << 3))]));
                acc[ks] = __builtin_amdgcn_mfma_f32_16x16x32_bf16(qf[kk], kf, acc[ks], 0, 0, 0);
            }
        }

        // online softmax (C/D: col=lr=key, row=lg*4+r=q); 16-lane xor-reduce
#pragma unroll
        for (int r = 0; r < 4; ++r) {
            float mx = fmaxf(fmaxf(acc[0][r], acc[1][r]), fmaxf(acc[2][r], acc[3][r]));
#pragma unroll
            for (int off = 8; off >= 1; off >>= 1)
                mx = fmaxf(mx, __shfl_xor(mx, off, 16));
            const float mn = fmaxf(m_run[r], mx);
            const float al = __expf(m_run[r] - mn);   // first tile: exp(-3e38)=0
            const float p0 = __expf(acc[0][r] - mn);
            const float p1 = __expf(acc[1][r] - mn);
            const float p2 = __expf(acc[2][r] - mn);
            const float p3 = __expf(acc[3][r] - mn);
            float rs = (p0 + p1) + (p2 + p3);
#pragma unroll
            for (int off = 8; off >= 1; off >>= 1)
                rs += __shfl_xor(rs, off, 16);
            l_run[r] = l_run[r] * al + rs;
            m_run[r] = mn;
#pragma unroll
            for (int ds = 0; ds < 8; ++ds) Oa[ds][r] *= al;
            const int q = lg * 4 + r;
            Ps[wid][q][0 * 16 + lr] = f2bf(p0);
            Ps[wid][q][1 * 16 + lr] = f2bf(p1);
            Ps[wid][q][2 * 16 + lr] = f2bf(p2);
            Ps[wid][q][3 * 16 + lr] = f2bf(p3);
        }
        __syncthreads();   // P visible (same wave, but safe + uniform)

        // O += P V : A = P[q=lr][m], B = V^T rows (d), 2 m-chunks x 8 d-subtiles
#pragma unroll
        for (int ms = 0; ms < 2; ++ms) {
            bf16x8 pf = __builtin_bit_cast(bf16x8,
                *reinterpret_cast<const ushortx8*>(&Ps[wid][lr][ms * 32 + lg * 8]));
#pragma unroll
            for (int ds = 0; ds < 8; ++ds) {
                const int d = ds * 16 + lr;
                const int m = ms * 32 + lg * 8;
                bf16x8 vf = __builtin_bit_cast(bf16x8,
                    *reinterpret_cast<const ushortx8*>(&Vs[d * 64 + (m ^ ((d & 7) << 3))]));
                Oa[ds] = __builtin_amdgcn_mfma_f32_16x16x32_bf16(pf, vf, Oa[ds], 0, 0, 0);
            }
        }
    }

    // epilogue: normalize and store (C/D: col=lr -> d, row=lg*4+r -> q)
#pragma unroll
    for (int r = 0; r < 4; ++r) {
        const float inv = 1.0f / l_run[r];
        unsigned short* orow = O + ((size_t)b * NN + (n_q0 + wid * 16 + lg * 4 + r)) * CC;
#pragma unroll
        for (int ds = 0; ds < 8; ++ds)
            orow[ds * 16 + lr] = f2bf(Oa[ds][r] * inv);
    }
}

// ---------------- Kernel 3: output conv + residual ----------------
__global__ __launch_bounds__(256) void out_conv(
    const unsigned short* __restrict__ O,   // [B][N][C] bf16
    const float* __restrict__ w_o, const float* __restrict__ b_o,
    const float* __restrict__ x,
    float* __restrict__ out)
{
    const int bid = blockIdx.x;
    const int b   = bid >> 6;
    const int n0  = (bid & 63) << 6;
    const int p   = threadIdx.x & 63;
    const int cg  = threadIdx.x >> 6;
    const int n   = n0 + p;

    float orr[CC];
    const unsigned short* orow = O + ((size_t)b * NN + n) * CC;
#pragma unroll
    for (int kk = 0; kk < CC / 8; ++kk) {
        ushortx8 u = *reinterpret_cast<const ushortx8*>(orow + kk * 8);
#pragma unroll
        for (int j = 0; j < 8; ++j) orr[kk * 8 + j] = bf2f(u[j]);
    }

    const int c0 = cg * 32;
    for (int ci = 0; ci < 32; ++ci) {
        const int c = c0 + ci;
        const float* wo = w_o + c * CC;   // uniform -> s_loads
        float acc = b_o[c];
#pragma unroll
        for (int k = 0; k < CC; ++k) acc = fmaf(wo[k], orr[k], acc);
        const size_t idx = ((size_t)b * CC + c) * NN + n;
        out[idx] = acc + x[idx];
    }
}

extern "C" void kernel_launch(void* const* d_in, const int* in_sizes, int n_in,
                              void* d_out, int out_size, void* d_ws, size_t ws_size,
                              hipStream_t stream)
{
    const float* x   = (const float*)d_in[0];
    const float* w_t = (const float*)d_in[1];
    const float* b_t = (const float*)d_in[2];
    const float* w_p = (const float*)d_in[3];
    const float* b_p = (const float*)d_in[4];
    const float* w_g = (const float*)d_in[5];
    const float* b_g = (const float*)d_in[6];
    const float* w_o = (const float*)d_in[7];
    const float* b_o = (const float*)d_in[8];
    float* out = (float*)d_out;

    unsigned short* Qw = (unsigned short*)d_ws;                 // 4 MB
    unsigned short* Kw = Qw + (size_t)BB * NN * CC;             // 4 MB
    unsigned short* Vw = Kw + (size_t)BB * NN * CC;             // 4 MB
    unsigned short* Ow = Vw + (size_t)BB * NN * CC;             // 4 MB

    proj_qkv <<<BB * (NN / 64), 256, 0, stream>>>(x, w_t, b_t, w_p, b_p, w_g, b_g, Qw, Kw, Vw);
    flash_attn<<<BB * (NN / 64), 256, 0, stream>>>(Qw, Kw, Vw, Ow);
    out_conv <<<BB * (NN / 64), 256, 0, stream>>>(Ow, w_o, b_o, x, out);
}

// Round 2
// 325.651 us; speedup vs baseline: 1.6395x; 1.6395x over previous
//
#include <hip/hip_runtime.h>
#include <hip/hip_bf16.h>

#define CC 128
#define BB 4
#define NN 4096

typedef __bf16 bf16x8 __attribute__((ext_vector_type(8)));
typedef float f32x4 __attribute__((ext_vector_type(4)));
typedef unsigned short ushortx8 __attribute__((ext_vector_type(8)));
typedef unsigned int uintx2 __attribute__((ext_vector_type(2)));

__device__ __forceinline__ float bf2f(unsigned short u) {
    unsigned int i = ((unsigned int)u) << 16;
    return __builtin_bit_cast(float, i);
}
__device__ __forceinline__ unsigned short f2bf(float f) {
    unsigned int i = __builtin_bit_cast(unsigned int, f);
    i = i + 0x7fffu + ((i >> 16) & 1u);   // RNE; inputs finite
    return (unsigned short)(i >> 16);
}
__device__ __forceinline__ unsigned int pack2bf(float a, float b) {
    return (unsigned int)f2bf(a) | ((unsigned int)f2bf(b) << 16);
}

// ---------------- Kernel 1: QKV projections ----------------
// Q[b][n][c] = theta, K[b][n][c] = phi  (row-major over c, MFMA-frag friendly)
// V[b][c][n] = g                        (d-major == V^T, PV-B-frag friendly)
__global__ __launch_bounds__(256) void proj_qkv(
    const float* __restrict__ x,
    const float* __restrict__ w_t, const float* __restrict__ b_t,
    const float* __restrict__ w_p, const float* __restrict__ b_p,
    const float* __restrict__ w_g, const float* __restrict__ b_g,
    unsigned short* __restrict__ Q,
    unsigned short* __restrict__ K,
    unsigned short* __restrict__ V)
{
    const int bid = blockIdx.x;
    const int b   = bid >> 6;
    const int n0  = (bid & 63) << 6;
    const int p   = threadIdx.x & 63;
    // wave-uniform c-quarter via readfirstlane -> weight loads become s_load
    const int cg  = __builtin_amdgcn_readfirstlane((int)(threadIdx.x >> 6));
    const int n   = n0 + p;

    // x[:, n] into registers (coalesced across lanes: consecutive n)
    float xr[CC];
    const float* xb = x + (size_t)b * CC * NN + n;
#pragma unroll
    for (int k = 0; k < CC; ++k) xr[k] = xb[(size_t)k * NN];

    const int c0 = cg * 32;
    for (int ci = 0; ci < 32; ++ci) {
        const int c = c0 + ci;                // uniform
        const float* wt = w_t + c * CC;       // uniform -> s_load
        const float* wp = w_p + c * CC;
        const float* wg = w_g + c * CC;
        float at = b_t[c], ap = b_p[c], ag = b_g[c];
#pragma unroll
        for (int k = 0; k < CC; ++k) {
            const float xv = xr[k];
            at = fmaf(wt[k], xv, at);
            ap = fmaf(wp[k], xv, ap);
            ag = fmaf(wg[k], xv, ag);
        }
        Q[((size_t)b * NN + n) * CC + c] = f2bf(at);
        K[((size_t)b * NN + n) * CC + c] = f2bf(ap);
        V[((size_t)b * CC + c) * NN + n] = f2bf(ag);
    }
}

// ---------------- Kernel 2: flash attention ----------------
// 4 waves/block; wave owns 16 q-rows; KV tile = 64 keys; D = 128.
// Swapped QK^T: mfma(K,Q) -> lane owns one q (col=lane&15), softmax in-lane.
__global__ __launch_bounds__(256) void flash_attn(
    const unsigned short* __restrict__ Q,   // [B][N][C]
    const unsigned short* __restrict__ K,   // [B][N][C]
    const unsigned short* __restrict__ V,   // [B][C][N]  (= V^T)
    unsigned short* __restrict__ O)         // [B][N][C]
{
    __shared__ alignas(16) unsigned short Ks[64 * 128];
    __shared__ alignas(16) unsigned short Vs[128 * 64];
    __shared__ alignas(16) unsigned short Ps[4][16][72];

    const int tid = threadIdx.x;
    const int bid = blockIdx.x;
    const int b    = bid >> 6;
    const int n_q0 = (bid & 63) << 6;
    const int wid  = tid >> 6;
    const int l    = tid & 63;
    const int lr   = l & 15;   // q for softmax state; row/col within 16
    const int lg   = l >> 4;   // k-group 0..3

    // Q fragment (B-frag of swapped QK): [q=lr][k = kk*32 + lg*8 + j]
    bf16x8 qf[4];
    {
        const unsigned short* qrow = Q + ((size_t)b * NN + (n_q0 + wid * 16 + lr)) * CC;
#pragma unroll
        for (int kk = 0; kk < 4; ++kk)
            qf[kk] = __builtin_bit_cast(bf16x8,
                *reinterpret_cast<const ushortx8*>(qrow + kk * 32 + lg * 8));
    }

    f32x4 Oa[8];
#pragma unroll
    for (int i = 0; i < 8; ++i) Oa[i] = (f32x4){0.f, 0.f, 0.f, 0.f};
    float m_run = -3.0e38f, l_run = 0.f;   // state for q = lr (replicated x4 groups)

    // staging registers (prefetch) + LDS store helpers
    ushortx8 pk[4], pv[4];

    const unsigned short* Kb = K + (size_t)b * NN * CC;
    const unsigned short* Vb = V + (size_t)b * CC * NN;

#define LOADT(m0)                                                              \
    {                                                                          \
        _Pragma("unroll")                                                      \
        for (int j = 0; j < 4; ++j) {                                          \
            const int i = tid + j * 256;                                       \
            const int r = i >> 4, c = (i & 15) * 8;                            \
            pk[j] = *reinterpret_cast<const ushortx8*>(Kb + ((size_t)(m0) + r) * CC + c); \
            const int d = i >> 3, m = (i & 7) * 8;                             \
            pv[j] = *reinterpret_cast<const ushortx8*>(Vb + (size_t)d * NN + (m0) + m);   \
        }                                                                      \
    }
#define STORET()                                                               \
    {                                                                          \
        _Pragma("unroll")                                                      \
        for (int j = 0; j < 4; ++j) {                                          \
            const int i = tid + j * 256;                                       \
            const int r = i >> 4, c = (i & 15) * 8;                            \
            *reinterpret_cast<ushortx8*>(&Ks[r * 128 + (c ^ ((r & 7) << 3))]) = pk[j]; \
            const int d = i >> 3, m = (i & 7) * 8;                             \
            *reinterpret_cast<ushortx8*>(&Vs[d * 64 + (m ^ ((d & 7) << 3))]) = pv[j];  \
        }                                                                      \
    }

    LOADT(0);
    STORET();
    __syncthreads();

    for (int kt = 0; kt < NN / 64; ++kt) {
        // prefetch next tile into registers; latency hides under QK+softmax+PV
        if (kt + 1 < NN / 64) LOADT((kt + 1) * 64);

        // S = K Q^T (swapped): D[key][q], col=lane&15=q, row=lg*4+reg=key-in-subtile
        f32x4 acc[4];
#pragma unroll
        for (int ks = 0; ks < 4; ++ks) {
            acc[ks] = (f32x4){0.f, 0.f, 0.f, 0.f};
#pragma unroll
            for (int kk = 0; kk < 4; ++kk) {
                const int r = ks * 16 + lr;          // key row in tile
                const int c = kk * 32 + lg * 8;      // k offset
                bf16x8 kf = __builtin_bit_cast(bf16x8,
                    *reinterpret_cast<const ushortx8*>(&Ks[r * 128 + (c ^ ((r & 7) << 3))]));
                acc[ks] = __builtin_amdgcn_mfma_f32_16x16x32_bf16(kf, qf[kk], acc[ks], 0, 0, 0);
            }
        }

        // ---- online softmax, per-lane (lane owns q=lr, 16 key-scores) ----
        float pmax = acc[0][0];
#pragma unroll
        for (int ks = 0; ks < 4; ++ks) {
            float t = fmaxf(fmaxf(acc[ks][0], acc[ks][1]), fmaxf(acc[ks][2], acc[ks][3]));
            pmax = (ks == 0) ? t : fmaxf(pmax, t);
        }
        pmax = fmaxf(pmax, __shfl_xor(pmax, 16));
        pmax = fmaxf(pmax, __shfl_xor(pmax, 32));

        // defer-max: only rescale when the running max grew by > 8
        if (!__all(pmax - m_run <= 8.f)) {
            const float mn = fmaxf(m_run, pmax);
            const float al = __expf(m_run - mn);
            m_run = mn;
            l_run *= al;
            float alq[4];
#pragma unroll
            for (int r = 0; r < 4; ++r) alq[r] = __shfl(al, lg * 4 + r, 16);
#pragma unroll
            for (int ds = 0; ds < 8; ++ds)
#pragma unroll
                for (int r = 0; r < 4; ++r) Oa[ds][r] *= alq[r];
        }

        float p[16];
#pragma unroll
        for (int ks = 0; ks < 4; ++ks)
#pragma unroll
            for (int r = 0; r < 4; ++r)
                p[ks * 4 + r] = __expf(acc[ks][r] - m_run);   // independent exps
        float rs = 0.f;
#pragma unroll
        for (int i = 0; i < 16; ++i) rs += p[i];
        rs += __shfl_xor(rs, 16);
        rs += __shfl_xor(rs, 32);
        l_run += rs;

        // P -> LDS: lane holds P[q=lr][key=ks*16+lg*4+r]; pack 4 keys -> b64
#pragma unroll
        for (int ks = 0; ks < 4; ++ks) {
            uintx2 wv;
            wv[0] = pack2bf(p[ks * 4 + 0], p[ks * 4 + 1]);
            wv[1] = pack2bf(p[ks * 4 + 2], p[ks * 4 + 3]);
            *reinterpret_cast<uintx2*>(&Ps[wid][lr][ks * 16 + lg * 4]) = wv;
        }
        // P is wave-private: no barrier needed (compiler inserts lgkmcnt)

        // O += P V : A = P[q][m], B = V^T rows (d)
#pragma unroll
        for (int ms = 0; ms < 2; ++ms) {
            bf16x8 pf = __builtin_bit_cast(bf16x8,
                *reinterpret_cast<const ushortx8*>(&Ps[wid][lr][ms * 32 + lg * 8]));
#pragma unroll
            for (int ds = 0; ds < 8; ++ds) {
                const int d = ds * 16 + lr;
                const int m = ms * 32 + lg * 8;
                bf16x8 vf = __builtin_bit_cast(bf16x8,
                    *reinterpret_cast<const ushortx8*>(&Vs[d * 64 + (m ^ ((d & 7) << 3))]));
                Oa[ds] = __builtin_amdgcn_mfma_f32_16x16x32_bf16(pf, vf, Oa[ds], 0, 0, 0);
            }
        }

        __syncthreads();   // all waves done reading Ks/Vs (also drains prefetch vmcnt)
        if (kt + 1 < NN / 64) {
            STORET();
            __syncthreads();   // staged tile visible
        }
    }

    // epilogue: normalize and store (Oa: col=lr -> d, row=lg*4+r -> q)
    float lq[4];
#pragma unroll
    for (int r = 0; r < 4; ++r) lq[r] = __shfl(l_run, lg * 4 + r, 16);
#pragma unroll
    for (int r = 0; r < 4; ++r) {
        const float inv = 1.0f / lq[r];
        unsigned short* orow = O + ((size_t)b * NN + (n_q0 + wid * 16 + lg * 4 + r)) * CC;
#pragma unroll
        for (int ds = 0; ds < 8; ++ds)
            orow[ds * 16 + lr] = f2bf(Oa[ds][r] * inv);
    }
#undef LOADT
#undef STORET
}

// ---------------- Kernel 3: output conv + residual ----------------
__global__ __launch_bounds__(256) void out_conv(
    const unsigned short* __restrict__ O,   // [B][N][C] bf16
    const float* __restrict__ w_o, const float* __restrict__ b_o,
    const float* __restrict__ x,
    float* __restrict__ out)
{
    const int bid = blockIdx.x;
    const int b   = bid >> 6;
    const int n0  = (bid & 63) << 6;
    const int p   = threadIdx.x & 63;
    const int cg  = __builtin_amdgcn_readfirstlane((int)(threadIdx.x >> 6));
    const int n   = n0 + p;

    float orr[CC];
    const unsigned short* orow = O + ((size_t)b * NN + n) * CC;
#pragma unroll
    for (int kk = 0; kk < CC / 8; ++kk) {
        ushortx8 u = *reinterpret_cast<const ushortx8*>(orow + kk * 8);
#pragma unroll
        for (int j = 0; j < 8; ++j) orr[kk * 8 + j] = bf2f(u[j]);
    }

    const int c0 = cg * 32;
    for (int ci = 0; ci < 32; ++ci) {
        const int c = c0 + ci;                // uniform
        const float* wo = w_o + c * CC;       // uniform -> s_load
        float acc = b_o[c];
#pragma unroll
        for (int k = 0; k < CC; ++k) acc = fmaf(wo[k], orr[k], acc);
        const size_t idx = ((size_t)b * CC + c) * NN + n;
        out[idx] = acc + x[idx];
    }
}

extern "C" void kernel_launch(void* const* d_in, const int* in_sizes, int n_in,
                              void* d_out, int out_size, void* d_ws, size_t ws_size,
                              hipStream_t stream)
{
    const float* x   = (const float*)d_in[0];
    const float* w_t = (const float*)d_in[1];
    const float* b_t = (const float*)d_in[2];
    const float* w_p = (const float*)d_in[3];
    const float* b_p = (const float*)d_in[4];
    const float* w_g = (const float*)d_in[5];
    const float* b_g = (const float*)d_in[6];
    const float* w_o = (const float*)d_in[7];
    const float* b_o = (const float*)d_in[8];
    float* out = (float*)d_out;

    unsigned short* Qw = (unsigned short*)d_ws;                 // 4 MB
    unsigned short* Kw = Qw + (size_t)BB * NN * CC;             // 4 MB
    unsigned short* Vw = Kw + (size_t)BB * NN * CC;             // 4 MB
    unsigned short* Ow = Vw + (size_t)BB * NN * CC;             // 4 MB

    proj_qkv <<<BB * (NN / 64), 256, 0, stream>>>(x, w_t, b_t, w_p, b_p, w_g, b_g, Qw, Kw, Vw);
    flash_attn<<<BB * (NN / 64), 256, 0, stream>>>(Qw, Kw, Vw, Ow);
    out_conv <<<BB * (NN / 64), 256, 0, stream>>>(Ow, w_o, b_o, x, out);
}